// Round 2
// baseline (594.123 us; speedup 1.0000x reference)
//
#include <hip/hip_runtime.h>

typedef short bf16x8 __attribute__((ext_vector_type(8)));
typedef float f32x4 __attribute__((ext_vector_type(4)));

#define HDIM 128
#define BM 32
#define PE 264   // e_in tile pitch (elems): 528B = 33*16 -> conflict-free b128
#define PT 136   // mid tile pitch (elems): 272B = 17*16

__device__ __forceinline__ unsigned short f2bf(float f) {
  union { float f; unsigned int u; } v; v.f = f;
  unsigned int r = v.u + 0x7fffu + ((v.u >> 16) & 1u);
  return (unsigned short)(r >> 16);
}
__device__ __forceinline__ float siluf(float x) { return x / (1.f + __expf(-x)); }
__device__ __forceinline__ f32x4 mfma16(bf16x8 a, bf16x8 b, f32x4 c) {
  return __builtin_amdgcn_mfma_f32_16x16x32_bf16(a, b, c, 0, 0, 0);
}

// ---------------- prep ----------------
__global__ void k_cast_h(const float* __restrict__ h, unsigned short* __restrict__ hbf, int n8) {
  int i = blockIdx.x * blockDim.x + threadIdx.x;
  if (i >= n8) return;
  const float4* s = (const float4*)(h + (size_t)i * 8);
  float4 a = s[0], b = s[1];
  union { unsigned short us[8]; uint4 q; } p;
  p.us[0] = f2bf(a.x); p.us[1] = f2bf(a.y); p.us[2] = f2bf(a.z); p.us[3] = f2bf(a.w);
  p.us[4] = f2bf(b.x); p.us[5] = f2bf(b.y); p.us[6] = f2bf(b.z); p.us[7] = f2bf(b.w);
  ((uint4*)hbf)[i] = p.q;
}

// Wt[n*K + k] = bf16(W[k*Nn + n])
__global__ void k_transpose(const float* __restrict__ W, unsigned short* __restrict__ Wt, int K, int Nn) {
  int i = blockIdx.x * blockDim.x + threadIdx.x;
  if (i >= K * Nn) return;
  int k = i / Nn, n = i - k * Nn;
  Wt[n * K + k] = f2bf(W[i]);
}

// ---------------- edge kernel ----------------
__global__ __launch_bounds__(256, 2)
void k_edge(const float* __restrict__ coord,
            const int* __restrict__ ei,
            const unsigned short* __restrict__ hbf,
            const unsigned short* __restrict__ We1t,
            const unsigned short* __restrict__ We2t,
            const unsigned short* __restrict__ Wc1t,
            const float* __restrict__ We1,   // [257][128], row 256 = radial row
            const float* __restrict__ be1,
            const float* __restrict__ be2,
            const float* __restrict__ bc1,
            const float* __restrict__ Wc2,   // [128]
            float* __restrict__ agg,
            float* __restrict__ sum_trans,
            float* __restrict__ cnt,
            int N, int E)
{
  __shared__ unsigned short e_in[BM * PE];
  __shared__ unsigned short m_t[BM * PT];
  __shared__ unsigned short ef_t[BM * PT];
  __shared__ float cd_lds[BM][3];
  __shared__ float rad_lds[BM];
  __shared__ float w_part[4][BM];
  __shared__ int rows_lds[BM];

  const int tid = threadIdx.x;
  const int lane = tid & 63;
  const int wv = tid >> 6;      // wave 0..3, owns cols [wv*32, wv*32+32)
  const int l15 = lane & 15;
  const int lg = lane >> 4;     // 0..3

  // ---- preload weight B-fragments into registers (per wave: its 32 cols) ----
  bf16x8 fW1[2][8], fW2[2][4], fW3[2][4];
  float bias1[2], bias2[2], bias3[2], wc2v[2], w256[2];
#pragma unroll
  for (int nt = 0; nt < 2; ++nt) {
    int n = wv * 32 + nt * 16 + l15;
#pragma unroll
    for (int kt = 0; kt < 8; ++kt)
      fW1[nt][kt] = *(const bf16x8*)&We1t[n * 256 + kt * 32 + lg * 8];
#pragma unroll
    for (int kt = 0; kt < 4; ++kt) {
      fW2[nt][kt] = *(const bf16x8*)&We2t[n * 128 + kt * 32 + lg * 8];
      fW3[nt][kt] = *(const bf16x8*)&Wc1t[n * 128 + kt * 32 + lg * 8];
    }
    bias1[nt] = be1[n]; bias2[nt] = be2[n]; bias3[nt] = bc1[n];
    wc2v[nt] = Wc2[n];
    w256[nt] = We1[256 * 128 + n];
  }

  const int ntiles = (E + BM - 1) / BM;
  for (int t = blockIdx.x; t < ntiles; t += gridDim.x) {
    const int e0 = t * BM;

    // ---- stage: indices, coord geometry, gather h rows into e_in ----
    if (tid < BM) {
      int e = e0 + tid;
      if (e < E) {
        int r = ei[e], c = ei[E + e];
        rows_lds[tid] = r;
        float dx = coord[r * 3 + 0] - coord[c * 3 + 0];
        float dy = coord[r * 3 + 1] - coord[c * 3 + 1];
        float dz = coord[r * 3 + 2] - coord[c * 3 + 2];
        cd_lds[tid][0] = dx; cd_lds[tid][1] = dy; cd_lds[tid][2] = dz;
        rad_lds[tid] = dx * dx + dy * dy + dz * dz;
      } else {
        rows_lds[tid] = -1;
        cd_lds[tid][0] = 0.f; cd_lds[tid][1] = 0.f; cd_lds[tid][2] = 0.f;
        rad_lds[tid] = 0.f;
      }
    }
    {
      // each thread copies 32 shorts (64 B): full coverage of 32 edges x 2 nodes x 128 shorts
      int slot = tid >> 2, part = tid & 3;
      int m = slot >> 1, half = slot & 1;
      int e = e0 + m;
      int node = 0;
      if (e < E) node = half ? ei[E + e] : ei[e];
      const uint4* src = (const uint4*)&hbf[(size_t)node * HDIM + part * 32];
      uint4 a = src[0], b = src[1], c = src[2], d = src[3];
      uint4* dst = (uint4*)&e_in[m * PE + half * HDIM + part * 32];
      dst[0] = a; dst[1] = b; dst[2] = c; dst[3] = d;
    }
    __syncthreads();

    // ---- layer 1: [32 x 256] @ We1[256 x 128] ----
    f32x4 acc[2][2];
#pragma unroll
    for (int mt = 0; mt < 2; ++mt)
#pragma unroll
      for (int nt = 0; nt < 2; ++nt)
        acc[mt][nt] = (f32x4){0.f, 0.f, 0.f, 0.f};
#pragma unroll
    for (int kt = 0; kt < 8; ++kt) {
      bf16x8 a0 = *(const bf16x8*)&e_in[l15 * PE + kt * 32 + lg * 8];
      bf16x8 a1 = *(const bf16x8*)&e_in[(16 + l15) * PE + kt * 32 + lg * 8];
#pragma unroll
      for (int nt = 0; nt < 2; ++nt) {
        acc[0][nt] = mfma16(a0, fW1[nt][kt], acc[0][nt]);
        acc[1][nt] = mfma16(a1, fW1[nt][kt], acc[1][nt]);
      }
    }
#pragma unroll
    for (int mt = 0; mt < 2; ++mt)
#pragma unroll
      for (int nt = 0; nt < 2; ++nt) {
        int n = wv * 32 + nt * 16 + l15;
#pragma unroll
        for (int r = 0; r < 4; ++r) {
          int m = mt * 16 + lg * 4 + r;
          float x = acc[mt][nt][r] + bias1[nt] + rad_lds[m] * w256[nt];
          m_t[m * PT + n] = f2bf(siluf(x));
        }
      }
    __syncthreads();

    // ---- layer 2: m @ We2 -> edge_feat; scatter into agg ----
    f32x4 acc2[2][2];
#pragma unroll
    for (int mt = 0; mt < 2; ++mt)
#pragma unroll
      for (int nt = 0; nt < 2; ++nt)
        acc2[mt][nt] = (f32x4){0.f, 0.f, 0.f, 0.f};
#pragma unroll
    for (int kt = 0; kt < 4; ++kt) {
      bf16x8 a0 = *(const bf16x8*)&m_t[l15 * PT + kt * 32 + lg * 8];
      bf16x8 a1 = *(const bf16x8*)&m_t[(16 + l15) * PT + kt * 32 + lg * 8];
#pragma unroll
      for (int nt = 0; nt < 2; ++nt) {
        acc2[0][nt] = mfma16(a0, fW2[nt][kt], acc2[0][nt]);
        acc2[1][nt] = mfma16(a1, fW2[nt][kt], acc2[1][nt]);
      }
    }
#pragma unroll
    for (int mt = 0; mt < 2; ++mt)
#pragma unroll
      for (int nt = 0; nt < 2; ++nt) {
        int n = wv * 32 + nt * 16 + l15;
#pragma unroll
        for (int r = 0; r < 4; ++r) {
          int m = mt * 16 + lg * 4 + r;
          float ef = siluf(acc2[mt][nt][r] + bias2[nt]);
          ef_t[m * PT + n] = f2bf(ef);
          int rr = rows_lds[m];
          if (rr >= 0) unsafeAtomicAdd(&agg[(size_t)rr * HDIM + n], ef);
        }
      }
    __syncthreads();

    // ---- layer 3: edge_feat @ Wc1 -> silu -> dot Wc2 -> per-edge scalar w ----
    f32x4 acc3[2][2];
#pragma unroll
    for (int mt = 0; mt < 2; ++mt)
#pragma unroll
      for (int nt = 0; nt < 2; ++nt)
        acc3[mt][nt] = (f32x4){0.f, 0.f, 0.f, 0.f};
#pragma unroll
    for (int kt = 0; kt < 4; ++kt) {
      bf16x8 a0 = *(const bf16x8*)&ef_t[l15 * PT + kt * 32 + lg * 8];
      bf16x8 a1 = *(const bf16x8*)&ef_t[(16 + l15) * PT + kt * 32 + lg * 8];
#pragma unroll
      for (int nt = 0; nt < 2; ++nt) {
        acc3[0][nt] = mfma16(a0, fW3[nt][kt], acc3[0][nt]);
        acc3[1][nt] = mfma16(a1, fW3[nt][kt], acc3[1][nt]);
      }
    }
    float vsum[2][4];
#pragma unroll
    for (int mt = 0; mt < 2; ++mt)
#pragma unroll
      for (int r = 0; r < 4; ++r) {
        float v = 0.f;
#pragma unroll
        for (int nt = 0; nt < 2; ++nt)
          v += siluf(acc3[mt][nt][r] + bias3[nt]) * wc2v[nt];
        vsum[mt][r] = v;
      }
#pragma unroll
    for (int mask = 1; mask < 16; mask <<= 1)
#pragma unroll
      for (int mt = 0; mt < 2; ++mt)
#pragma unroll
        for (int r = 0; r < 4; ++r)
          vsum[mt][r] += __shfl_xor(vsum[mt][r], mask);
    if (l15 == 0) {
#pragma unroll
      for (int mt = 0; mt < 2; ++mt)
#pragma unroll
        for (int r = 0; r < 4; ++r)
          w_part[wv][mt * 16 + lg * 4 + r] = vsum[mt][r];
    }
    __syncthreads();

    // ---- finalize coord scatter ----
    if (tid < BM && rows_lds[tid] >= 0) {
      float w = w_part[0][tid] + w_part[1][tid] + w_part[2][tid] + w_part[3][tid];
      int rr = rows_lds[tid];
      unsafeAtomicAdd(&sum_trans[(size_t)rr * 3 + 0], cd_lds[tid][0] * w);
      unsafeAtomicAdd(&sum_trans[(size_t)rr * 3 + 1], cd_lds[tid][1] * w);
      unsafeAtomicAdd(&sum_trans[(size_t)rr * 3 + 2], cd_lds[tid][2] * w);
      unsafeAtomicAdd(&cnt[rr], 1.f);
    }
    __syncthreads();
  }
}

// ---------------- node kernel ----------------
__global__ __launch_bounds__(256, 2)
void k_node(const float* __restrict__ h,
            const unsigned short* __restrict__ hbf,
            const float* __restrict__ agg,
            const unsigned short* __restrict__ Wn1t,
            const unsigned short* __restrict__ Wn2t,
            const float* __restrict__ bn1,
            const float* __restrict__ bn2,
            float* __restrict__ hout,
            int N)
{
  __shared__ unsigned short a_in[BM * PE];
  __shared__ unsigned short t1[BM * PT];
  const int tid = threadIdx.x, lane = tid & 63, wv = tid >> 6;
  const int l15 = lane & 15, lg = lane >> 4;

  bf16x8 fW1[2][8], fW2[2][4];
  float b1v[2], b2v[2];
#pragma unroll
  for (int nt = 0; nt < 2; ++nt) {
    int n = wv * 32 + nt * 16 + l15;
#pragma unroll
    for (int kt = 0; kt < 8; ++kt)
      fW1[nt][kt] = *(const bf16x8*)&Wn1t[n * 256 + kt * 32 + lg * 8];
#pragma unroll
    for (int kt = 0; kt < 4; ++kt)
      fW2[nt][kt] = *(const bf16x8*)&Wn2t[n * 128 + kt * 32 + lg * 8];
    b1v[nt] = bn1[n]; b2v[nt] = bn2[n];
  }

  const int ntiles = (N + BM - 1) / BM;
  for (int t = blockIdx.x; t < ntiles; t += gridDim.x) {
    const int base = t * BM;
    {
      int slot = tid >> 2, part = tid & 3;
      int m = slot >> 1, half = slot & 1;
      int node = base + m; if (node >= N) node = N - 1;
      if (half == 0) {
        const uint4* src = (const uint4*)&hbf[(size_t)node * HDIM + part * 32];
        uint4 a = src[0], b = src[1], c = src[2], d = src[3];
        uint4* dst = (uint4*)&a_in[m * PE + part * 32];
        dst[0] = a; dst[1] = b; dst[2] = c; dst[3] = d;
      } else {
        const float4* s = (const float4*)&agg[(size_t)node * HDIM + part * 32];
        union { unsigned short us[32]; uint4 q[4]; } p;
#pragma unroll
        for (int j = 0; j < 8; ++j) {
          float4 v = s[j];
          p.us[j * 4 + 0] = f2bf(v.x); p.us[j * 4 + 1] = f2bf(v.y);
          p.us[j * 4 + 2] = f2bf(v.z); p.us[j * 4 + 3] = f2bf(v.w);
        }
        uint4* dst = (uint4*)&a_in[m * PE + HDIM + part * 32];
        dst[0] = p.q[0]; dst[1] = p.q[1]; dst[2] = p.q[2]; dst[3] = p.q[3];
      }
    }
    __syncthreads();

    f32x4 acc[2][2];
#pragma unroll
    for (int mt = 0; mt < 2; ++mt)
#pragma unroll
      for (int nt = 0; nt < 2; ++nt)
        acc[mt][nt] = (f32x4){0.f, 0.f, 0.f, 0.f};
#pragma unroll
    for (int kt = 0; kt < 8; ++kt) {
      bf16x8 a0 = *(const bf16x8*)&a_in[l15 * PE + kt * 32 + lg * 8];
      bf16x8 a1 = *(const bf16x8*)&a_in[(16 + l15) * PE + kt * 32 + lg * 8];
#pragma unroll
      for (int nt = 0; nt < 2; ++nt) {
        acc[0][nt] = mfma16(a0, fW1[nt][kt], acc[0][nt]);
        acc[1][nt] = mfma16(a1, fW1[nt][kt], acc[1][nt]);
      }
    }
#pragma unroll
    for (int mt = 0; mt < 2; ++mt)
#pragma unroll
      for (int nt = 0; nt < 2; ++nt) {
        int n = wv * 32 + nt * 16 + l15;
#pragma unroll
        for (int r = 0; r < 4; ++r) {
          int m = mt * 16 + lg * 4 + r;
          t1[m * PT + n] = f2bf(siluf(acc[mt][nt][r] + b1v[nt]));
        }
      }
    __syncthreads();

    f32x4 acc2[2][2];
#pragma unroll
    for (int mt = 0; mt < 2; ++mt)
#pragma unroll
      for (int nt = 0; nt < 2; ++nt)
        acc2[mt][nt] = (f32x4){0.f, 0.f, 0.f, 0.f};
#pragma unroll
    for (int kt = 0; kt < 4; ++kt) {
      bf16x8 a0 = *(const bf16x8*)&t1[l15 * PT + kt * 32 + lg * 8];
      bf16x8 a1 = *(const bf16x8*)&t1[(16 + l15) * PT + kt * 32 + lg * 8];
#pragma unroll
      for (int nt = 0; nt < 2; ++nt) {
        acc2[0][nt] = mfma16(a0, fW2[nt][kt], acc2[0][nt]);
        acc2[1][nt] = mfma16(a1, fW2[nt][kt], acc2[1][nt]);
      }
    }
#pragma unroll
    for (int mt = 0; mt < 2; ++mt)
#pragma unroll
      for (int nt = 0; nt < 2; ++nt) {
        int n = wv * 32 + nt * 16 + l15;
#pragma unroll
        for (int r = 0; r < 4; ++r) {
          int node = base + mt * 16 + lg * 4 + r;
          if (node < N)
            hout[(size_t)node * HDIM + n] = h[(size_t)node * HDIM + n] + acc2[mt][nt][r] + b2v[nt];
        }
      }
    __syncthreads();
  }
}

// ---------------- coord epilogue ----------------
__global__ void k_coord(const float* __restrict__ coord,
                        const float* __restrict__ sum_trans,
                        const float* __restrict__ cnt,
                        float* __restrict__ out, int N) {
  int i = blockIdx.x * blockDim.x + threadIdx.x;
  if (i >= N * 3) return;
  int node = i / 3;
  float c = cnt[node]; if (c < 1.f) c = 1.f;
  out[i] = coord[i] + sum_trans[i] / c;
}

extern "C" void kernel_launch(void* const* d_in, const int* in_sizes, int n_in,
                              void* d_out, int out_size, void* d_ws, size_t ws_size,
                              hipStream_t stream) {
  const float* h     = (const float*)d_in[0];
  const float* coord = (const float*)d_in[1];
  const int*   ei    = (const int*)d_in[2];
  const float* We1   = (const float*)d_in[3];
  const float* be1   = (const float*)d_in[4];
  const float* We2   = (const float*)d_in[5];
  const float* be2   = (const float*)d_in[6];
  const float* Wn1   = (const float*)d_in[7];
  const float* bn1   = (const float*)d_in[8];
  const float* Wn2   = (const float*)d_in[9];
  const float* bn2   = (const float*)d_in[10];
  const float* Wc1   = (const float*)d_in[11];
  const float* bc1   = (const float*)d_in[12];
  const float* Wc2   = (const float*)d_in[13];

  const int N = in_sizes[0] / HDIM;
  const int E = in_sizes[2] / 2;

  char* ws = (char*)d_ws;
  size_t off = 0;
  auto alloc = [&](size_t b) { void* p = ws + off; off = (off + b + 255) & ~(size_t)255; return p; };
  unsigned short* hbf  = (unsigned short*)alloc((size_t)N * HDIM * 2);
  unsigned short* We1t = (unsigned short*)alloc(256 * 128 * 2);
  unsigned short* We2t = (unsigned short*)alloc(128 * 128 * 2);
  unsigned short* Wc1t = (unsigned short*)alloc(128 * 128 * 2);
  unsigned short* Wn1t = (unsigned short*)alloc(256 * 128 * 2);
  unsigned short* Wn2t = (unsigned short*)alloc(128 * 128 * 2);
  float* agg = (float*)alloc((size_t)N * (HDIM + 4) * 4);  // agg | sum_trans | cnt (contiguous)
  float* sum_trans = agg + (size_t)N * HDIM;
  float* cnt = sum_trans + (size_t)N * 3;

  hipMemsetAsync(agg, 0, (size_t)N * (HDIM + 4) * 4, stream);

  int n8 = N * HDIM / 8;
  k_cast_h<<<(n8 + 255) / 256, 256, 0, stream>>>(h, hbf, n8);
  k_transpose<<<(256 * 128 + 255) / 256, 256, 0, stream>>>(We1, We1t, 256, 128);
  k_transpose<<<(128 * 128 + 255) / 256, 256, 0, stream>>>(We2, We2t, 128, 128);
  k_transpose<<<(128 * 128 + 255) / 256, 256, 0, stream>>>(Wc1, Wc1t, 128, 128);
  k_transpose<<<(256 * 128 + 255) / 256, 256, 0, stream>>>(Wn1, Wn1t, 256, 128);
  k_transpose<<<(128 * 128 + 255) / 256, 256, 0, stream>>>(Wn2, Wn2t, 128, 128);

  k_edge<<<1024, 256, 0, stream>>>(coord, ei, hbf, We1t, We2t, Wc1t, We1,
                                   be1, be2, bc1, Wc2, agg, sum_trans, cnt, N, E);

  float* hout = (float*)d_out;
  k_node<<<512, 256, 0, stream>>>(h, hbf, agg, Wn1t, Wn2t, bn1, bn2, hout, N);
  k_coord<<<(N * 3 + 255) / 256, 256, 0, stream>>>(coord, sum_trans, cnt,
                                                   hout + (size_t)N * HDIM, N);
}